// Round 5
// baseline (866.097 us; speedup 1.0000x reference)
//
#include <hip/hip_runtime.h>

// ---------------------------------------------------------------------------
// GAT (5 layers, 8 heads / last 1 head) + final linear.
// GEMMs: split-bf16 (hi+lo) MFMA, fp32 accumulate -> fp32-level accuracy at
// MFMA rate. dst-CSR built once; fused online-softmax + aggregation per node
// (gathers h in fp32, writes next layer's bf16 hi/lo planes directly).
// ---------------------------------------------------------------------------

typedef short short8 __attribute__((ext_vector_type(8)));
typedef float floatx4 __attribute__((ext_vector_type(4)));

__device__ __forceinline__ unsigned short f2bf(float f) {
  unsigned u = __float_as_uint(f);
  return (unsigned short)((u + 0x7FFF + ((u >> 16) & 1)) >> 16);  // RNE
}
__device__ __forceinline__ float bf2f(unsigned short h) {
  return __uint_as_float(((unsigned)h) << 16);
}

// ---------------- CSR build ----------------
__global__ __launch_bounds__(256) void k_deg_init(int* deg, int n) {
  int i = blockIdx.x * 256 + threadIdx.x;
  if (i < n) deg[i] = 1;  // self loop
}

__global__ __launch_bounds__(256) void k_count(const int* __restrict__ ei, int E, int* deg) {
  int i = blockIdx.x * 256 + threadIdx.x;
  if (i < E) atomicAdd(&deg[ei[E + i]], 1);
}

__device__ __forceinline__ int block_excl_scan(int v, int* tot) {
  __shared__ int wsum[4];
  int lane = threadIdx.x & 63, w = threadIdx.x >> 6;
  int x = v;
  #pragma unroll
  for (int off = 1; off < 64; off <<= 1) {
    int y = __shfl_up(x, off);
    if (lane >= off) x += y;
  }
  if (lane == 63) wsum[w] = x;
  __syncthreads();
  int wbase = 0;
  #pragma unroll
  for (int i = 0; i < 4; i++) wbase += (i < w) ? wsum[i] : 0;
  if (tot) *tot = wsum[0] + wsum[1] + wsum[2] + wsum[3];
  return wbase + x - v;
}

__global__ __launch_bounds__(256) void k_bsum(const int* __restrict__ deg, int* __restrict__ bsum, int n) {
  int i = blockIdx.x * 256 + threadIdx.x;
  int v = (i < n) ? deg[i] : 0;
  int tot;
  block_excl_scan(v, &tot);
  if (threadIdx.x == 0) bsum[blockIdx.x] = tot;
}

__global__ __launch_bounds__(256) void k_bscan(const int* __restrict__ bsum, int* __restrict__ boff, int nb) {
  int t = threadIdx.x;
  int v = (t < nb) ? bsum[t] : 0;
  int ex = block_excl_scan(v, nullptr);
  if (t < nb) boff[t] = ex;
}

__global__ __launch_bounds__(256) void k_rowptr(const int* __restrict__ deg,
                                                const int* __restrict__ boff,
                                                int* __restrict__ row_ptr,
                                                int* __restrict__ cursor, int n) {
  int i = blockIdx.x * 256 + threadIdx.x;
  int v = (i < n) ? deg[i] : 0;
  int ex = block_excl_scan(v, nullptr) + boff[blockIdx.x];
  if (i < n) { row_ptr[i] = ex; cursor[i] = ex; }
  if (i == n - 1) row_ptr[n] = ex + v;
}

__global__ __launch_bounds__(256) void k_fill(const int* __restrict__ ei, int E, int n,
                                              int* cursor, int* __restrict__ srcs) {
  int i = blockIdx.x * 256 + threadIdx.x;
  if (i >= E + n) return;
  int s, d;
  if (i < E) { s = ei[i]; d = ei[E + i]; }
  else       { s = i - E; d = s; }
  int slot = atomicAdd(&cursor[d], 1);
  srcs[slot] = s;
}

// ---------------- fp32 -> split-bf16 planes ----------------
__global__ __launch_bounds__(256) void k_cvt(const float* __restrict__ x,
                                             unsigned short* __restrict__ hi,
                                             unsigned short* __restrict__ lo, int n4) {
  int i = blockIdx.x * 256 + threadIdx.x;
  if (i >= n4) return;
  float4 v = ((const float4*)x)[i];
  ushort4 h, l;
  h.x = f2bf(v.x); l.x = f2bf(v.x - bf2f(h.x));
  h.y = f2bf(v.y); l.y = f2bf(v.y - bf2f(h.y));
  h.z = f2bf(v.z); l.z = f2bf(v.z - bf2f(h.z));
  h.w = f2bf(v.w); l.w = f2bf(v.w - bf2f(h.w));
  ((ushort4*)hi)[i] = h;
  ((ushort4*)lo)[i] = l;
}

// ---------------------------------------------------------------------------
// C[M,128] = A[M,128] @ W[128,128] (+bias,+relu) via split-bf16 MFMA.
// A given as hi/lo bf16 planes; W fp32, converted + transposed into
// XOR-swizzled LDS once per block. 256 thr = 4 waves x 16 rows.
// mfma_f32_16x16x32_bf16: A[lane&15][(lane>>4)*8+i], B[(lane>>4)*8+i][lane&15],
// C col=lane&15, row=(lane>>4)*4+reg (m89-verified layout).
// ---------------------------------------------------------------------------
__global__ __launch_bounds__(256) void k_gemm_bf(const unsigned short* __restrict__ Ahi,
                                                 const unsigned short* __restrict__ Alo,
                                                 const float* __restrict__ W,
                                                 const float* __restrict__ bias,
                                                 float* __restrict__ C, int M, int relu) {
  __shared__ unsigned short WtHi[128 * 128];  // [n][k ^ ((n&7)<<3)]
  __shared__ unsigned short WtLo[128 * 128];
  int tid = threadIdx.x;
  // stage W: fp32 [k][n] -> transposed swizzled bf16 hi/lo
  #pragma unroll
  for (int r = 0; r < 16; r++) {
    int idx = r * 1024 + tid * 4;          // linear over [k][n]
    int k = idx >> 7, n = idx & 127;
    float4 w4 = *(const float4*)(W + idx);
    float wf[4] = {w4.x, w4.y, w4.z, w4.w};
    #pragma unroll
    for (int e = 0; e < 4; e++) {
      int row = n + e;
      unsigned short hh = f2bf(wf[e]);
      unsigned short ll = f2bf(wf[e] - bf2f(hh));
      int di = row * 128 + (k ^ ((row & 7) << 3));
      WtHi[di] = hh; WtLo[di] = ll;
    }
  }
  __syncthreads();

  int lane = tid & 63;
  int wv = tid >> 6;
  int m0 = blockIdx.x * 64 + wv * 16;
  int lr = lane & 15;    // A-row within 16-tile / C-col within 16-tile
  int kb = lane >> 4;    // k sub-block (8 elems)
  int arow = m0 + lr; if (arow >= M) arow = M - 1;   // clamp (stores guarded)
  const size_t abase = (size_t)arow * 128;

  short8 ahi[4], alo[4];
  #pragma unroll
  for (int j = 0; j < 4; j++) {
    int k0 = j * 32 + kb * 8;
    ahi[j] = *(const short8*)(Ahi + abase + k0);
    alo[j] = *(const short8*)(Alo + abase + k0);
  }

  floatx4 acc[8];
  #pragma unroll
  for (int nt = 0; nt < 8; nt++) acc[nt] = (floatx4){0.f, 0.f, 0.f, 0.f};

  #pragma unroll
  for (int j = 0; j < 4; j++) {          // K step of 32
    #pragma unroll
    for (int nt = 0; nt < 8; nt++) {     // N tile of 16
      int n = nt * 16 + lr;
      int k0 = j * 32 + kb * 8;
      int di = n * 128 + (k0 ^ ((n & 7) << 3));
      short8 bhi = *(const short8*)(WtHi + di);
      short8 blo = *(const short8*)(WtLo + di);
      acc[nt] = __builtin_amdgcn_mfma_f32_16x16x32_bf16(ahi[j], bhi, acc[nt], 0, 0, 0);
      acc[nt] = __builtin_amdgcn_mfma_f32_16x16x32_bf16(ahi[j], blo, acc[nt], 0, 0, 0);
      acc[nt] = __builtin_amdgcn_mfma_f32_16x16x32_bf16(alo[j], bhi, acc[nt], 0, 0, 0);
    }
  }

  #pragma unroll
  for (int nt = 0; nt < 8; nt++) {
    int col = nt * 16 + lr;
    #pragma unroll
    for (int r = 0; r < 4; r++) {
      int row = m0 + kb * 4 + r;
      if (row < M) {
        float v = acc[nt][r];
        if (bias) v += bias[col];
        if (relu) v = fmaxf(v, 0.f);
        C[(size_t)row * 128 + col] = v;
      }
    }
  }
}

// ---------------- attention logits ----------------
__global__ __launch_bounds__(256) void k_al8(const float* __restrict__ h,
                                             const float* __restrict__ a_s,
                                             const float* __restrict__ a_d,
                                             float* __restrict__ als, float* __restrict__ ald, int n) {
  int g = blockIdx.x * 256 + threadIdx.x;
  if (g >= n * 8) return;
  int hd = g & 7;
  const float4* hp = (const float4*)(h + (size_t)g * 16);
  const float4* ap = (const float4*)(a_s + hd * 16);
  const float4* dp = (const float4*)(a_d + hd * 16);
  float ss = 0.f, sd = 0.f;
  #pragma unroll
  for (int i = 0; i < 4; i++) {
    float4 hv = hp[i], av = ap[i], dv = dp[i];
    ss += hv.x * av.x + hv.y * av.y + hv.z * av.z + hv.w * av.w;
    sd += hv.x * dv.x + hv.y * dv.y + hv.z * dv.z + hv.w * dv.w;
  }
  als[g] = ss; ald[g] = sd;
}

__global__ __launch_bounds__(256) void k_al1(const float* __restrict__ h,
                                             const float* __restrict__ a_s,
                                             const float* __restrict__ a_d,
                                             float* __restrict__ als, float* __restrict__ ald, int n) {
  int g = blockIdx.x * 256 + threadIdx.x;
  int v = g >> 4, q = g & 15;
  bool act = (v < n);
  float ss = 0.f, sd = 0.f;
  if (act) {
    float4 hv = *(const float4*)(h + (size_t)v * 128 + q * 4);
    float4 av = *(const float4*)(a_s + q * 4);
    float4 dv = *(const float4*)(a_d + q * 4);
    ss = hv.x * av.x + hv.y * av.y + hv.z * av.z + hv.w * av.w;
    sd = hv.x * dv.x + hv.y * dv.y + hv.z * dv.z + hv.w * dv.w;
  }
  #pragma unroll
  for (int off = 1; off < 16; off <<= 1) { ss += __shfl_xor(ss, off); sd += __shfl_xor(sd, off); }
  if (act && q == 0) { als[v] = ss; ald[v] = sd; }
}

// ---------------------------------------------------------------------------
// Fused per-node online-softmax + aggregation; one wave per destination node.
// Output written directly as split-bf16 planes (next GEMM's A).
// ---------------------------------------------------------------------------
template <int H>
__global__ __launch_bounds__(256) void k_agg(const int* __restrict__ row_ptr,
                                             const int* __restrict__ srcs,
                                             const float* __restrict__ als,
                                             const float* __restrict__ ald,
                                             const float* __restrict__ h,
                                             const float* __restrict__ bias,
                                             unsigned short* __restrict__ outHi,
                                             unsigned short* __restrict__ outLo, int n) {
  const int EPP = 64 / H;
  int lane = threadIdx.x & 63;
  int wv = threadIdx.x >> 6;
  int v = blockIdx.x * 4 + wv;
  bool active = (v < n);
  int s0 = 0, s1 = 0;
  int eo = lane / H;
  int hd = lane % H;
  float ed = 0.f;
  if (active) { s0 = row_ptr[v]; s1 = row_ptr[v + 1]; ed = ald[v * H + hd]; }
  // pass 1: online softmax (m, d)
  float m = -1e30f, d = 0.f;
  for (int j = s0 + eo; j < s1; j += EPP) {
    int sv = srcs[j];
    float e = als[sv * H + hd] + ed;
    e = (e > 0.f) ? e : 0.2f * e;
    float nm = fmaxf(m, e);
    d = d * __expf(m - nm) + __expf(e - nm);
    m = nm;
  }
  #pragma unroll
  for (int off = H; off < 64; off <<= 1) {
    float om = __shfl_xor(m, off);
    float od = __shfl_xor(d, off);
    float nm = fmaxf(m, om);
    d = d * __expf(m - nm) + od * __expf(om - nm);
    m = nm;
  }
  // pass 2: aggregation (2 edge slots x 32 channel-lanes x float4)
  int slot = lane >> 5;
  int l5 = lane & 31;
  int c0 = l5 * 4;
  int hd3 = (H == 1) ? 0 : (c0 / (128 / H));
  float m3 = __shfl(m, hd3);
  float inv = 1.f / __shfl(d, hd3);
  float ed3 = __shfl(ed, hd3);
  float ax = 0.f, ay = 0.f, az = 0.f, aw = 0.f;
  #pragma unroll 2
  for (int j = s0 + slot; j < s1; j += 2) {
    int sv = srcs[j];
    float e = als[sv * H + hd3] + ed3;
    e = (e > 0.f) ? e : 0.2f * e;
    float al = __expf(e - m3) * inv;
    float4 hv = *(const float4*)(h + (size_t)sv * 128 + c0);
    ax += al * hv.x; ay += al * hv.y; az += al * hv.z; aw += al * hv.w;
  }
  ax += __shfl_xor(ax, 32);
  ay += __shfl_xor(ay, 32);
  az += __shfl_xor(az, 32);
  aw += __shfl_xor(aw, 32);
  if (active && slot == 0) {
    float o[4];
    o[0] = fmaxf(ax + bias[c0 + 0], 0.f);
    o[1] = fmaxf(ay + bias[c0 + 1], 0.f);
    o[2] = fmaxf(az + bias[c0 + 2], 0.f);
    o[3] = fmaxf(aw + bias[c0 + 3], 0.f);
    ushort4 h4, l4;
    h4.x = f2bf(o[0]); l4.x = f2bf(o[0] - bf2f(h4.x));
    h4.y = f2bf(o[1]); l4.y = f2bf(o[1] - bf2f(h4.y));
    h4.z = f2bf(o[2]); l4.z = f2bf(o[2] - bf2f(h4.z));
    h4.w = f2bf(o[3]); l4.w = f2bf(o[3] - bf2f(h4.w));
    *(ushort4*)(outHi + (size_t)v * 128 + c0) = h4;
    *(ushort4*)(outLo + (size_t)v * 128 + c0) = l4;
  }
}

extern "C" void kernel_launch(void* const* d_in, const int* in_sizes, int n_in,
                              void* d_out, int out_size, void* d_ws, size_t ws_size,
                              hipStream_t stream) {
  const float* x  = (const float*)d_in[0];
  const int*   ei = (const int*)d_in[1];
  const int N  = in_sizes[0] / 128;
  const int E  = in_sizes[1] / 2;
  const int ET = E + N;
  const int NB = (N + 255) / 256;

  const float *Wl[5], *as[5], *ad[5], *bl[5];
  for (int l = 0; l < 5; l++) {
    Wl[l] = (const float*)d_in[3 + 4 * l];
    as[l] = (const float*)d_in[4 + 4 * l];
    ad[l] = (const float*)d_in[5 + 4 * l];
    bl[l] = (const float*)d_in[6 + 4 * l];
  }
  const float* W_lin = (const float*)d_in[23];
  const float* b_lin = (const float*)d_in[24];

  char* p = (char*)d_ws;
  auto alloc = [&](size_t bytes) { void* r = (void*)p; p += (bytes + 255) & ~size_t(255); return r; };
  float* h    = (float*)alloc((size_t)N * 128 * 4);
  unsigned short* pAhi = (unsigned short*)alloc((size_t)N * 128 * 2);
  unsigned short* pAlo = (unsigned short*)alloc((size_t)N * 128 * 2);
  unsigned short* pBhi = (unsigned short*)alloc((size_t)N * 128 * 2);
  unsigned short* pBlo = (unsigned short*)alloc((size_t)N * 128 * 2);
  float* als  = (float*)alloc((size_t)N * 8 * 4);
  float* ald  = (float*)alloc((size_t)N * 8 * 4);
  int* row_ptr = (int*)alloc((size_t)(N + 1) * 4);
  int* cursor  = (int*)alloc((size_t)N * 4);
  int* deg     = (int*)alloc((size_t)N * 4);
  int* srcs    = (int*)alloc((size_t)ET * 4);
  int* bsum    = (int*)alloc((size_t)NB * 4);
  int* boff    = (int*)alloc((size_t)NB * 4);
  (void)ws_size; (void)n_in; (void)out_size;

  dim3 b256(256);
  // CSR build (once; reused across all 5 layers)
  k_deg_init<<<NB, b256, 0, stream>>>(deg, N);
  k_count<<<(E + 255) / 256, b256, 0, stream>>>(ei, E, deg);
  k_bsum<<<NB, b256, 0, stream>>>(deg, bsum, N);
  k_bscan<<<1, b256, 0, stream>>>(bsum, boff, NB);
  k_rowptr<<<NB, b256, 0, stream>>>(deg, boff, row_ptr, cursor, N);
  k_fill<<<(ET + 255) / 256, b256, 0, stream>>>(ei, E, N, cursor, srcs);

  // x -> split-bf16 planes
  int n4 = N * 128 / 4;
  k_cvt<<<(n4 + 255) / 256, b256, 0, stream>>>(x, pAhi, pAlo, n4);

  int gemm_grid = (N + 63) / 64;
  unsigned short *inHi = pAhi, *inLo = pAlo, *outHi = pBhi, *outLo = pBlo;
  for (int l = 0; l < 5; l++) {
    k_gemm_bf<<<gemm_grid, b256, 0, stream>>>(inHi, inLo, Wl[l], nullptr, h, N, 0);
    if (l < 4) {
      k_al8<<<(N * 8 + 255) / 256, b256, 0, stream>>>(h, as[l], ad[l], als, ald, N);
      k_agg<8><<<(N + 3) / 4, b256, 0, stream>>>(row_ptr, srcs, als, ald, h, bl[l], outHi, outLo, N);
    } else {
      k_al1<<<(N * 16 + 255) / 256, b256, 0, stream>>>(h, as[l], ad[l], als, ald, N);
      k_agg<1><<<(N + 3) / 4, b256, 0, stream>>>(row_ptr, srcs, als, ald, h, bl[l], outHi, outLo, N);
    }
    unsigned short* t;
    t = inHi; inHi = outHi; outHi = t;
    t = inLo; inLo = outLo; outLo = t;
  }
  k_gemm_bf<<<gemm_grid, b256, 0, stream>>>(inHi, inLo, W_lin, b_lin, (float*)d_out, N, 1);
}